// Round 3
// baseline (425.229 us; speedup 1.0000x reference)
//
#include <hip/hip_runtime.h>
#include <cstdint>
#include <cstring>

// ---------------------------------------------------------------------------
// GQA forward, all-bf16 MFMA pipeline.  B=2, L=2048, D=2048, HQ=32, HKV=8, HD=64.
// Round 3: pre-transposed V (GEMM1 epilogue), pure global_load_lds staging in
// attention, 64-k tiles (17.4 KB LDS), k-split x2 + merge kernel for occupancy.
// ---------------------------------------------------------------------------

#define L_SEQ 2048
#define D_MODEL 2048
#define M_ROWS 4096              // B*L
#define KV_COLS 512              // HKV*HD
#define ATTN_SCALE 0.18033688011112042f   // log2(e)/sqrt(64), folded into K

typedef __bf16 bf16x8 __attribute__((ext_vector_type(8)));
typedef float f32x4 __attribute__((ext_vector_type(4)));
typedef float f32x16 __attribute__((ext_vector_type(16)));

__device__ __forceinline__ f32x4 zero4() {
    f32x4 v; v[0] = 0.f; v[1] = 0.f; v[2] = 0.f; v[3] = 0.f; return v;
}

__device__ __forceinline__ unsigned short f2bf(float x) {
    unsigned u = __builtin_bit_cast(unsigned, x);
    u = (u + 0x7FFFu + ((u >> 16) & 1u)) >> 16;   // RNE
    return (unsigned short)u;
}
__device__ __forceinline__ float bf2fs(unsigned short h) {
    unsigned u = ((unsigned)h) << 16;
    return __builtin_bit_cast(float, u);
}

__device__ __forceinline__ unsigned pk_bf16(float a, float b) {
#if __has_builtin(__builtin_amdgcn_cvt_pk_bf16_f32)
    typedef __bf16 bf16x2 __attribute__((ext_vector_type(2)));
    bf16x2 r = __builtin_amdgcn_cvt_pk_bf16_f32(a, b);
    return __builtin_bit_cast(unsigned, r);
#else
    return (unsigned)f2bf(a) | ((unsigned)f2bf(b) << 16);
#endif
}

__device__ __forceinline__ f32x4 mfma16(uint4 a, uint4 b, f32x4 c) {
    return __builtin_amdgcn_mfma_f32_16x16x32_bf16(
        __builtin_bit_cast(bf16x8, a), __builtin_bit_cast(bf16x8, b), c, 0, 0, 0);
}
__device__ __forceinline__ f32x16 mfma32(uint4 a, uint4 b, f32x16 c) {
    return __builtin_amdgcn_mfma_f32_32x32x16_bf16(
        __builtin_bit_cast(bf16x8, a), __builtin_bit_cast(bf16x8, b), c, 0, 0, 0);
}

__device__ __forceinline__ void gl_lds16(const unsigned short* g, unsigned short* l) {
    __builtin_amdgcn_global_load_lds(
        (const __attribute__((address_space(1))) unsigned int*)g,
        (__attribute__((address_space(3))) unsigned int*)l, 16, 0, 0);
}

#if __has_builtin(__builtin_amdgcn_exp2f)
#define EXP2F(x) __builtin_amdgcn_exp2f(x)
#else
#define EXP2F(x) exp2f(x)
#endif

// ---------------------------------------------------------------------------
// prep kernels
// ---------------------------------------------------------------------------

__global__ __launch_bounds__(256) void cast_x_kernel(const float* __restrict__ in,
                                                     unsigned short* __restrict__ out,
                                                     int n4) {
    int i = blockIdx.x * 256 + threadIdx.x;
    if (i >= n4) return;
    float4 v = ((const float4*)in)[i];
    uint2 o;
    o.x = pk_bf16(v.x, v.y);
    o.y = pk_bf16(v.z, v.w);
    ((uint2*)out)[i] = o;
}

__global__ __launch_bounds__(256) void transpose_cast_kernel(const float* __restrict__ in,
                                                             unsigned short* __restrict__ out,
                                                             int N, int row_off) {
    __shared__ float tile[32][33];
    const int n0 = blockIdx.x * 32, k0 = blockIdx.y * 32;
    const int tc = threadIdx.x & 31, tr = threadIdx.x >> 5;
#pragma unroll
    for (int i = 0; i < 4; ++i)
        tile[tr + i * 8][tc] = in[(size_t)(k0 + tr + i * 8) * N + n0 + tc];
    __syncthreads();
#pragma unroll
    for (int i = 0; i < 4; ++i)
        out[(size_t)(row_off + n0 + tr + i * 8) * 2048 + k0 + tc] = f2bf(tile[tc][tr + i * 8]);
}

// ---------------------------------------------------------------------------
// GEMM core (m97 structure): C[128x128] = A[M,2048] * Bt[N,2048]^T
// ---------------------------------------------------------------------------

__device__ __forceinline__ void gemm_core_2048(const unsigned short* __restrict__ A,
                                               const unsigned short* __restrict__ Bt,
                                               int m_block, int n_block,
                                               unsigned short* smA, unsigned short* smB,
                                               f32x4 acc[4][4]) {
    const int tid = threadIdx.x;
    const int w = tid >> 6, lane = tid & 63;
    const int wm = w >> 1, wn = w & 1;
    const int lr = lane & 15, lg = lane >> 4;

#pragma unroll
    for (int i = 0; i < 4; ++i)
#pragma unroll
        for (int j = 0; j < 4; ++j) acc[i][j] = zero4();

    const int rowA = m_block * 128 + w * 32 + (lane >> 2);
    const int rowB = n_block * 128 + w * 32 + (lane >> 2);
    const int kcol = (lane & 3) * 8;
    const unsigned short* gA0 = A + (size_t)rowA * 2048 + kcol;
    const unsigned short* gA1 = gA0 + (size_t)16 * 2048;
    const unsigned short* gB0 = Bt + (size_t)rowB * 2048 + kcol;
    const unsigned short* gB1 = gB0 + (size_t)16 * 2048;
    unsigned short* lA0 = smA + (w * 32) * 32;
    unsigned short* lA1 = smA + (w * 32 + 16) * 32;
    unsigned short* lB0 = smB + (w * 32) * 32;
    unsigned short* lB1 = smB + (w * 32 + 16) * 32;

    for (int kt = 0; kt < 64; ++kt) {
        gl_lds16(gA0 + kt * 32, lA0);
        gl_lds16(gA1 + kt * 32, lA1);
        gl_lds16(gB0 + kt * 32, lB0);
        gl_lds16(gB1 + kt * 32, lB1);
        __syncthreads();
        uint4 af[4], bfg[4];
#pragma unroll
        for (int i = 0; i < 4; ++i)
            af[i] = *(const uint4*)(smA + (wm * 64 + i * 16 + lr) * 32 + lg * 8);
#pragma unroll
        for (int j = 0; j < 4; ++j)
            bfg[j] = *(const uint4*)(smB + (wn * 64 + j * 16 + lr) * 32 + lg * 8);
#pragma unroll
        for (int i = 0; i < 4; ++i)
#pragma unroll
            for (int j = 0; j < 4; ++j)
                acc[i][j] = mfma16(af[i], bfg[j], acc[i][j]);
        __syncthreads();
    }
}

// GEMM1: X*[Wq|Wk|Wv] + bias.  Q row-major [4096,2048]; K row-major [4096,512]
// pre-scaled by ATTN_SCALE; V written TRANSPOSED: Vt[((b*8+kvh)*64+d)][l], l in [0,2048).
__global__ __launch_bounds__(256) void gemm_qkv_kernel(
    const unsigned short* __restrict__ Xb, const unsigned short* __restrict__ Wt,
    const float* __restrict__ bq, const float* __restrict__ bk, const float* __restrict__ bv,
    unsigned short* __restrict__ Qb, unsigned short* __restrict__ Kb,
    unsigned short* __restrict__ Vt) {
    __shared__ __align__(16) unsigned short smA[128 * 32];
    __shared__ __align__(16) unsigned short smB[128 * 32];
    f32x4 acc[4][4];
    gemm_core_2048(Xb, Wt, blockIdx.x, blockIdx.y, smA, smB, acc);

    const int tid = threadIdx.x;
    const int w = tid >> 6, lane = tid & 63;
    const int wm = w >> 1, wn = w & 1;
    const int lr = lane & 15, lg = lane >> 4;
    const int nbase = blockIdx.y * 128;

    if (nbase >= 2560) {
        // ---- V branch: transposed store ----
#pragma unroll
        for (int i = 0; i < 4; ++i) {
            const int mrow = blockIdx.x * 128 + wm * 64 + i * 16 + lg * 4;
            const int b = mrow >> 11, l = mrow & 2047;
#pragma unroll
            for (int j = 0; j < 4; ++j) {
                const int nloc = nbase + wn * 64 + j * 16 + lr - 2560;   // 0..511
                const int kvh = nloc >> 6, d = nloc & 63;
                const float bb = bv[nloc];
                uint2 pv;
                pv.x = pk_bf16(acc[i][j][0] + bb, acc[i][j][1] + bb);
                pv.y = pk_bf16(acc[i][j][2] + bb, acc[i][j][3] + bb);
                *(uint2*)(Vt + ((size_t)((b * 8 + kvh) * 64 + d)) * 2048 + l) = pv;
            }
        }
        return;
    }

    unsigned short* outp; int ldo, noff; const float* bias; float scale;
    if (nbase < 2048)      { outp = Qb; ldo = 2048; noff = 0;    bias = bq; scale = 1.f; }
    else                   { outp = Kb; ldo = 512;  noff = 2048; bias = bk; scale = ATTN_SCALE; }

#pragma unroll
    for (int i = 0; i < 4; ++i) {
        const int mrow = blockIdx.x * 128 + wm * 64 + i * 16 + lg * 4;
#pragma unroll
        for (int j = 0; j < 4; ++j) {
            const int nloc = nbase + wn * 64 + j * 16 + lr - noff;
            const float bb = bias[nloc];
#pragma unroll
            for (int r = 0; r < 4; ++r)
                outp[(size_t)(mrow + r) * ldo + nloc] = f2bf((acc[i][j][r] + bb) * scale);
        }
    }
}

// GEMM2: ctx * Wo^T + bo -> fp32 out [4096,2048]
__global__ __launch_bounds__(256) void gemm_out_kernel(
    const unsigned short* __restrict__ Cb, const unsigned short* __restrict__ Wot,
    const float* __restrict__ bo, float* __restrict__ out) {
    __shared__ __align__(16) unsigned short smA[128 * 32];
    __shared__ __align__(16) unsigned short smB[128 * 32];
    f32x4 acc[4][4];
    gemm_core_2048(Cb, Wot, blockIdx.x, blockIdx.y, smA, smB, acc);

    const int tid = threadIdx.x;
    const int w = tid >> 6, lane = tid & 63;
    const int wm = w >> 1, wn = w & 1;
    const int lr = lane & 15, lg = lane >> 4;

#pragma unroll
    for (int i = 0; i < 4; ++i) {
        const int mrow = blockIdx.x * 128 + wm * 64 + i * 16 + lg * 4;
#pragma unroll
        for (int j = 0; j < 4; ++j) {
            const int ncol = blockIdx.y * 128 + wn * 64 + j * 16 + lr;
            const float bb = bo[ncol];
#pragma unroll
            for (int r = 0; r < 4; ++r)
                out[(size_t)(mrow + r) * 2048 + ncol] = acc[i][j][r] + bb;
        }
    }
}

// ---------------------------------------------------------------------------
// Attention v3: S^T = K*Q^T (32x32x16), O^T = V^T*P^T, in-register P frags.
// k-split x2: grid z = b*2 + half, each block covers k in [half*1024, +1024).
// K tile [64][64] + V^T tile [64][64] in LDS, both staged via global_load_lds
// with source-side chunk-XOR swizzle.  Unnormalized partial O (bf16) + l (f32).
// ---------------------------------------------------------------------------

__global__ __launch_bounds__(256, 6) void attn_kernel(
    const unsigned short* __restrict__ Qb, const unsigned short* __restrict__ Kb,
    const unsigned short* __restrict__ Vtg,
    unsigned short* __restrict__ Po0, unsigned short* __restrict__ Po1,
    float* __restrict__ Ls) {
    __shared__ __align__(16) unsigned short smem[8704];   // 17408 B
    unsigned short* ks = smem;          // [64 k][64 d], chunk-swizzled
    unsigned short* vt = smem + 4096;   // [64 d][64 k], chunk-swizzled

    const int qt = blockIdx.x, hq = blockIdx.y;
    const int b = blockIdx.z >> 1, half = blockIdx.z & 1;
    const int kvh = hq >> 2;
    const int tid = threadIdx.x;
    const int w = tid >> 6, lane = tid & 63;
    const int l31 = lane & 31, h = lane >> 5;

    // Q B-frags: B[n=q][k=d], n=lane&31, k=h*8+j ; 4 frags over d=64
    const int qrow = b * L_SEQ + qt * 128 + w * 32 + l31;
    const unsigned short* qp = Qb + (size_t)qrow * 2048 + hq * 64;
    uint4 qf[4];
#pragma unroll
    for (int dh = 0; dh < 4; ++dh) qf[dh] = *(const uint4*)(qp + dh * 16 + h * 8);

    f32x16 o0, o1;
#pragma unroll
    for (int r = 0; r < 16; ++r) { o0[r] = 0.f; o1[r] = 0.f; }
    float l_acc = 0.f;

    const size_t kbase = (size_t)(b * L_SEQ) * KV_COLS + kvh * 64;
    const size_t vbase = (size_t)((b * 8 + kvh) * 64) * 2048;
    const int rr = lane >> 3;                  // row within an 8-row staging block
    const int swl = (lane & 7) ^ rr;           // source chunk swizzle

    for (int t = 0; t < 16; ++t) {
        const int k0 = half * 1024 + t * 64;
#pragma unroll
        for (int s2 = 0; s2 < 2; ++s2) {
            const int blk = w * 2 + s2;
            const int row = blk * 8 + rr;
            gl_lds16(Kb + kbase + (size_t)(k0 + row) * KV_COLS + swl * 8, ks + blk * 512);
            gl_lds16(Vtg + vbase + (size_t)row * 2048 + k0 + swl * 8, vt + blk * 512);
        }
        __syncthreads();

#pragma unroll
        for (int c = 0; c < 2; ++c) {
            // ---- S^T = K*Q^T over 32 k-rows ----
            f32x16 s;
#pragma unroll
            for (int r = 0; r < 16; ++r) s[r] = 0.f;
#pragma unroll
            for (int dh = 0; dh < 4; ++dh) {
                uint4 kf = *(const uint4*)&ks[(c * 32 + l31) * 64 +
                                              (((dh * 2 + h) ^ (l31 & 7)) * 8)];
                s = mfma32(kf, qf[dh], s);
            }
            // ---- p = exp2(s) (scale pre-folded into K) ----
            unsigned E[4][2];
            float lsum = 0.f;
#pragma unroll
            for (int g = 0; g < 4; ++g) {
                float e0 = EXP2F(s[4 * g + 0]);
                float e1 = EXP2F(s[4 * g + 1]);
                float e2 = EXP2F(s[4 * g + 2]);
                float e3 = EXP2F(s[4 * g + 3]);
                lsum += (e0 + e1) + (e2 + e3);
                E[g][0] = pk_bf16(e0, e1);
                E[g][1] = pk_bf16(e2, e3);
            }
            l_acc += lsum;
            // ---- P^T B-frags (2 shfl per frag) + PV ----
#pragma unroll
            for (int tau = 0; tau < 2; ++tau) {
                unsigned pub0 = h ? E[2 * tau][0] : E[2 * tau + 1][0];
                unsigned pub1 = h ? E[2 * tau][1] : E[2 * tau + 1][1];
                unsigned R0 = (unsigned)__shfl_xor((int)pub0, 32, 64);
                unsigned R1 = (unsigned)__shfl_xor((int)pub1, 32, 64);
                uint4 pf;
                pf.x = h ? R0 : E[2 * tau][0];
                pf.y = h ? R1 : E[2 * tau][1];
                pf.z = h ? E[2 * tau + 1][0] : R0;
                pf.w = h ? E[2 * tau + 1][1] : R1;
                const int ch = ((c * 4 + tau * 2 + h) ^ (l31 & 7)) * 8;
                uint4 vf0 = *(const uint4*)&vt[(size_t)l31 * 64 + ch];
                uint4 vf1 = *(const uint4*)&vt[(size_t)(32 + l31) * 64 + ch];
                o0 = mfma32(vf0, pf, o0);
                o1 = mfma32(vf1, pf, o1);
            }
        }
        __syncthreads();
    }

    // ---- l partial (f32) ----
    float l_tot = l_acc + __shfl_xor(l_acc, 32, 64);
    if (h == 0)
        Ls[(size_t)half * (M_ROWS * 32) + (size_t)qrow * 32 + hq] = l_tot;

    // ---- epilogue: transpose O^T via per-wave LDS region, store bf16 partial ----
    __syncthreads();   // all waves done with ks/vt
    unsigned short* po = half ? Po1 : Po0;
    unsigned* ep = (unsigned*)smem + w * 1088;   // 32 rows x 34 dwords
#pragma unroll
    for (int dt = 0; dt < 2; ++dt) {
        const f32x16& o = dt ? o1 : o0;
#pragma unroll
        for (int g = 0; g < 4; ++g)
#pragma unroll
            for (int p = 0; p < 2; ++p) {
                const int dv = dt * 16 + 4 * g + 2 * h + p;
                ep[l31 * 34 + dv] = pk_bf16(o[4 * g + 2 * p], o[4 * g + 2 * p + 1]);
            }
    }
    __builtin_amdgcn_s_waitcnt(0);   // wave-local LDS visibility
#pragma unroll
    for (int p = 0; p < 4; ++p) {
        const int qr = (lane >> 3) + p * 8;
        const int cch = lane & 7;
        uint4 vv = *(const uint4*)((const unsigned short*)ep + qr * 68 + cch * 8);
        *(uint4*)(po + (size_t)(b * L_SEQ + qt * 128 + w * 32 + qr) * 2048 +
                  hq * 64 + cch * 8) = vv;
    }
}

// ---------------------------------------------------------------------------
// merge: ctx = (O0 + O1) / (l0 + l1), bf16 out.  1M threads, 8 elems each.
// ---------------------------------------------------------------------------

__global__ __launch_bounds__(256) void merge_kernel(
    const unsigned short* __restrict__ Po0, const unsigned short* __restrict__ Po1,
    const float* __restrict__ Ls, unsigned short* __restrict__ ctx) {
    const int gid = blockIdx.x * 256 + threadIdx.x;
    const int row = gid >> 8, c8 = gid & 255;
    const int hq = c8 >> 3;
    const float l = Ls[(size_t)row * 32 + hq] + Ls[(size_t)(M_ROWS * 32) + (size_t)row * 32 + hq];
    const float rl = 1.f / l;
    const uint4 a = ((const uint4*)(Po0 + (size_t)row * 2048))[c8];
    const uint4 bq4 = ((const uint4*)(Po1 + (size_t)row * 2048))[c8];
    const unsigned ua[4] = {a.x, a.y, a.z, a.w};
    const unsigned ub[4] = {bq4.x, bq4.y, bq4.z, bq4.w};
    uint4 res;
    unsigned rr[4];
#pragma unroll
    for (int k = 0; k < 4; ++k) {
        const float lo = bf2fs((unsigned short)(ua[k] & 0xffff)) +
                         bf2fs((unsigned short)(ub[k] & 0xffff));
        const float hi = bf2fs((unsigned short)(ua[k] >> 16)) +
                         bf2fs((unsigned short)(ub[k] >> 16));
        rr[k] = pk_bf16(lo * rl, hi * rl);
    }
    res.x = rr[0]; res.y = rr[1]; res.z = rr[2]; res.w = rr[3];
    *(uint4*)(ctx + (size_t)row * 2048 + c8 * 8) = res;
}

// ---------------------------------------------------------------------------

extern "C" void kernel_launch(void* const* d_in, const int* in_sizes, int n_in,
                              void* d_out, int out_size, void* d_ws, size_t ws_size,
                              hipStream_t stream) {
    const float* x  = (const float*)d_in[0];
    const float* Wq = (const float*)d_in[1];
    const float* bq = (const float*)d_in[2];
    const float* Wk = (const float*)d_in[3];
    const float* bk = (const float*)d_in[4];
    const float* Wv = (const float*)d_in[5];
    const float* bv = (const float*)d_in[6];
    const float* Wo = (const float*)d_in[7];
    const float* bo = (const float*)d_in[8];
    float* out = (float*)d_out;

    char* ws = (char*)d_ws;
    size_t off = 0;
    auto alloc = [&](size_t bytes) {
        char* p = ws + off;
        off += (bytes + 255) & ~(size_t)255;
        return p;
    };
    unsigned short* Wqkvt = (unsigned short*)alloc((size_t)3072 * 2048 * 2);   // 12.6 MB
    unsigned short* Wot   = (unsigned short*)alloc((size_t)2048 * 2048 * 2);   //  8.4 MB
    unsigned short* Xb    = (unsigned short*)alloc((size_t)M_ROWS * 2048 * 2); // 16.8 MB
    unsigned short* Qb    = (unsigned short*)alloc((size_t)M_ROWS * 2048 * 2); // 16.8 MB
    unsigned short* Kb    = (unsigned short*)alloc((size_t)M_ROWS * KV_COLS * 2);
    unsigned short* Vt    = (unsigned short*)alloc((size_t)M_ROWS * KV_COLS * 2);
    unsigned short* Po1   = (unsigned short*)alloc((size_t)M_ROWS * 2048 * 2); // 16.8 MB
    float*          Ls    = (float*)alloc((size_t)2 * M_ROWS * 32 * 4);        //  1.0 MB
    unsigned short* Po0   = Xb;   // Xb dead after GEMM1
    unsigned short* Cb    = Qb;   // Qb dead after attn; merge writes ctx here

    cast_x_kernel<<<(M_ROWS * 2048 / 4 + 255) / 256, 256, 0, stream>>>(x, Xb,
                                                                       M_ROWS * 2048 / 4);
    transpose_cast_kernel<<<dim3(64, 64), 256, 0, stream>>>(Wq, Wqkvt, 2048, 0);
    transpose_cast_kernel<<<dim3(16, 64), 256, 0, stream>>>(Wk, Wqkvt, 512, 2048);
    transpose_cast_kernel<<<dim3(16, 64), 256, 0, stream>>>(Wv, Wqkvt, 512, 2560);
    transpose_cast_kernel<<<dim3(64, 64), 256, 0, stream>>>(Wo, Wot, 2048, 0);
    gemm_qkv_kernel<<<dim3(32, 24), 256, 0, stream>>>(Xb, Wqkvt, bq, bk, bv, Qb, Kb, Vt);
    attn_kernel<<<dim3(16, 32, 4), 256, 0, stream>>>(Qb, Kb, Vt, Po0, Po1, Ls);
    merge_kernel<<<M_ROWS * 2048 / 8 / 256, 256, 0, stream>>>(Po0, Po1, Ls, Cb);
    gemm_out_kernel<<<dim3(32, 16), 256, 0, stream>>>(Cb, Wot, bo, out);
}

// Round 4
// 347.711 us; speedup vs baseline: 1.2229x; 1.2229x over previous
//
#include <hip/hip_runtime.h>
#include <cstdint>
#include <cstring>

// ---------------------------------------------------------------------------
// GQA forward, all-bf16 MFMA pipeline.  B=2, L=2048, D=2048, HQ=32, HKV=8, HD=64.
// Round 4: no k-split.  Attention waves own 64 q (2 q-frags) so each K/V LDS
// fragment read feeds 2 MFMAs; K and V^T both staged via global_load_lds with
// source-side XOR swizzle; V^T produced by a coalesced transpose kernel.
// ---------------------------------------------------------------------------

#define L_SEQ 2048
#define D_MODEL 2048
#define M_ROWS 4096              // B*L
#define KV_COLS 512              // HKV*HD
#define ATTN_SCALE 0.18033688011112042f   // log2(e)/sqrt(64), folded into K

typedef __bf16 bf16x8 __attribute__((ext_vector_type(8)));
typedef float f32x4 __attribute__((ext_vector_type(4)));
typedef float f32x16 __attribute__((ext_vector_type(16)));

__device__ __forceinline__ f32x4 zero4() {
    f32x4 v; v[0] = 0.f; v[1] = 0.f; v[2] = 0.f; v[3] = 0.f; return v;
}

__device__ __forceinline__ unsigned short f2bf(float x) {
    unsigned u = __builtin_bit_cast(unsigned, x);
    u = (u + 0x7FFFu + ((u >> 16) & 1u)) >> 16;   // RNE
    return (unsigned short)u;
}

__device__ __forceinline__ unsigned pk_bf16(float a, float b) {
#if __has_builtin(__builtin_amdgcn_cvt_pk_bf16_f32)
    typedef __bf16 bf16x2 __attribute__((ext_vector_type(2)));
    bf16x2 r = __builtin_amdgcn_cvt_pk_bf16_f32(a, b);
    return __builtin_bit_cast(unsigned, r);
#else
    return (unsigned)f2bf(a) | ((unsigned)f2bf(b) << 16);
#endif
}

__device__ __forceinline__ f32x4 mfma16(uint4 a, uint4 b, f32x4 c) {
    return __builtin_amdgcn_mfma_f32_16x16x32_bf16(
        __builtin_bit_cast(bf16x8, a), __builtin_bit_cast(bf16x8, b), c, 0, 0, 0);
}
__device__ __forceinline__ f32x16 mfma32(uint4 a, uint4 b, f32x16 c) {
    return __builtin_amdgcn_mfma_f32_32x32x16_bf16(
        __builtin_bit_cast(bf16x8, a), __builtin_bit_cast(bf16x8, b), c, 0, 0, 0);
}

__device__ __forceinline__ void gl_lds16(const unsigned short* g, unsigned short* l) {
    __builtin_amdgcn_global_load_lds(
        (const __attribute__((address_space(1))) unsigned int*)g,
        (__attribute__((address_space(3))) unsigned int*)l, 16, 0, 0);
}

#if __has_builtin(__builtin_amdgcn_exp2f)
#define EXP2F(x) __builtin_amdgcn_exp2f(x)
#else
#define EXP2F(x) exp2f(x)
#endif

// ---------------------------------------------------------------------------
// prep kernels
// ---------------------------------------------------------------------------

__global__ __launch_bounds__(256) void cast_x_kernel(const float* __restrict__ in,
                                                     unsigned short* __restrict__ out,
                                                     int n4) {
    int i = blockIdx.x * 256 + threadIdx.x;
    if (i >= n4) return;
    float4 v = ((const float4*)in)[i];
    uint2 o;
    o.x = pk_bf16(v.x, v.y);
    o.y = pk_bf16(v.z, v.w);
    ((uint2*)out)[i] = o;
}

__global__ __launch_bounds__(256) void transpose_cast_kernel(const float* __restrict__ in,
                                                             unsigned short* __restrict__ out,
                                                             int N, int row_off) {
    __shared__ float tile[32][33];
    const int n0 = blockIdx.x * 32, k0 = blockIdx.y * 32;
    const int tc = threadIdx.x & 31, tr = threadIdx.x >> 5;
#pragma unroll
    for (int i = 0; i < 4; ++i)
        tile[tr + i * 8][tc] = in[(size_t)(k0 + tr + i * 8) * N + n0 + tc];
    __syncthreads();
#pragma unroll
    for (int i = 0; i < 4; ++i)
        out[(size_t)(row_off + n0 + tr + i * 8) * 2048 + k0 + tc] = f2bf(tile[tc][tr + i * 8]);
}

// Vb [B*L, 512] bf16  ->  Vt [(b*8+kvh)*64+d, 2048] bf16  (per-b transpose)
__global__ __launch_bounds__(256) void transpose_v_kernel(const unsigned short* __restrict__ Vb,
                                                          unsigned short* __restrict__ Vt) {
    __shared__ unsigned short tile[32][33];
    const int c0 = blockIdx.x * 32, l0 = blockIdx.y * 32, b = blockIdx.z;
    const int tc = threadIdx.x & 31, tr = threadIdx.x >> 5;
#pragma unroll
    for (int i = 0; i < 4; ++i)
        tile[tr + i * 8][tc] = Vb[(size_t)(b * 2048 + l0 + tr + i * 8) * KV_COLS + c0 + tc];
    __syncthreads();
#pragma unroll
    for (int i = 0; i < 4; ++i)
        Vt[(size_t)(b * 512 + c0 + tr + i * 8) * 2048 + l0 + tc] = tile[tc][tr + i * 8];
}

// ---------------------------------------------------------------------------
// GEMM core (m97 structure): C[128x128] = A[M,2048] * Bt[N,2048]^T
// ---------------------------------------------------------------------------

__device__ __forceinline__ void gemm_core_2048(const unsigned short* __restrict__ A,
                                               const unsigned short* __restrict__ Bt,
                                               int m_block, int n_block,
                                               unsigned short* smA, unsigned short* smB,
                                               f32x4 acc[4][4]) {
    const int tid = threadIdx.x;
    const int w = tid >> 6, lane = tid & 63;
    const int wm = w >> 1, wn = w & 1;
    const int lr = lane & 15, lg = lane >> 4;

#pragma unroll
    for (int i = 0; i < 4; ++i)
#pragma unroll
        for (int j = 0; j < 4; ++j) acc[i][j] = zero4();

    const int rowA = m_block * 128 + w * 32 + (lane >> 2);
    const int rowB = n_block * 128 + w * 32 + (lane >> 2);
    const int kcol = (lane & 3) * 8;
    const unsigned short* gA0 = A + (size_t)rowA * 2048 + kcol;
    const unsigned short* gA1 = gA0 + (size_t)16 * 2048;
    const unsigned short* gB0 = Bt + (size_t)rowB * 2048 + kcol;
    const unsigned short* gB1 = gB0 + (size_t)16 * 2048;
    unsigned short* lA0 = smA + (w * 32) * 32;
    unsigned short* lA1 = smA + (w * 32 + 16) * 32;
    unsigned short* lB0 = smB + (w * 32) * 32;
    unsigned short* lB1 = smB + (w * 32 + 16) * 32;

    for (int kt = 0; kt < 64; ++kt) {
        gl_lds16(gA0 + kt * 32, lA0);
        gl_lds16(gA1 + kt * 32, lA1);
        gl_lds16(gB0 + kt * 32, lB0);
        gl_lds16(gB1 + kt * 32, lB1);
        __syncthreads();
        uint4 af[4], bfg[4];
#pragma unroll
        for (int i = 0; i < 4; ++i)
            af[i] = *(const uint4*)(smA + (wm * 64 + i * 16 + lr) * 32 + lg * 8);
#pragma unroll
        for (int j = 0; j < 4; ++j)
            bfg[j] = *(const uint4*)(smB + (wn * 64 + j * 16 + lr) * 32 + lg * 8);
#pragma unroll
        for (int i = 0; i < 4; ++i)
#pragma unroll
            for (int j = 0; j < 4; ++j)
                acc[i][j] = mfma16(af[i], bfg[j], acc[i][j]);
        __syncthreads();
    }
}

// GEMM1: X*[Wq|Wk|Wv] + bias -> Q [4096,2048], K [4096,512] (pre-scaled), V [4096,512]
__global__ __launch_bounds__(256) void gemm_qkv_kernel(
    const unsigned short* __restrict__ Xb, const unsigned short* __restrict__ Wt,
    const float* __restrict__ bq, const float* __restrict__ bk, const float* __restrict__ bv,
    unsigned short* __restrict__ Qb, unsigned short* __restrict__ Kb,
    unsigned short* __restrict__ Vb) {
    __shared__ __align__(16) unsigned short smA[128 * 32];
    __shared__ __align__(16) unsigned short smB[128 * 32];
    f32x4 acc[4][4];
    gemm_core_2048(Xb, Wt, blockIdx.x, blockIdx.y, smA, smB, acc);

    const int tid = threadIdx.x;
    const int w = tid >> 6, lane = tid & 63;
    const int wm = w >> 1, wn = w & 1;
    const int lr = lane & 15, lg = lane >> 4;
    const int nbase = blockIdx.y * 128;

    unsigned short* outp; int ldo, noff; const float* bias; float scale;
    if (nbase < 2048)      { outp = Qb; ldo = 2048; noff = 0;    bias = bq; scale = 1.f; }
    else if (nbase < 2560) { outp = Kb; ldo = 512;  noff = 2048; bias = bk; scale = ATTN_SCALE; }
    else                   { outp = Vb; ldo = 512;  noff = 2560; bias = bv; scale = 1.f; }

#pragma unroll
    for (int i = 0; i < 4; ++i) {
        const int mrow = blockIdx.x * 128 + wm * 64 + i * 16 + lg * 4;
#pragma unroll
        for (int j = 0; j < 4; ++j) {
            const int nloc = nbase + wn * 64 + j * 16 + lr - noff;
            const float bb = bias[nloc];
#pragma unroll
            for (int r = 0; r < 4; ++r)
                outp[(size_t)(mrow + r) * ldo + nloc] = f2bf((acc[i][j][r] + bb) * scale);
        }
    }
}

// GEMM2: ctx * Wo^T + bo -> fp32 out [4096,2048]
__global__ __launch_bounds__(256) void gemm_out_kernel(
    const unsigned short* __restrict__ Cb, const unsigned short* __restrict__ Wot,
    const float* __restrict__ bo, float* __restrict__ out) {
    __shared__ __align__(16) unsigned short smA[128 * 32];
    __shared__ __align__(16) unsigned short smB[128 * 32];
    f32x4 acc[4][4];
    gemm_core_2048(Cb, Wot, blockIdx.x, blockIdx.y, smA, smB, acc);

    const int tid = threadIdx.x;
    const int w = tid >> 6, lane = tid & 63;
    const int wm = w >> 1, wn = w & 1;
    const int lr = lane & 15, lg = lane >> 4;

#pragma unroll
    for (int i = 0; i < 4; ++i) {
        const int mrow = blockIdx.x * 128 + wm * 64 + i * 16 + lg * 4;
#pragma unroll
        for (int j = 0; j < 4; ++j) {
            const int ncol = blockIdx.y * 128 + wn * 64 + j * 16 + lr;
            const float bb = bo[ncol];
#pragma unroll
            for (int r = 0; r < 4; ++r)
                out[(size_t)(mrow + r) * 2048 + ncol] = acc[i][j][r] + bb;
        }
    }
}

// ---------------------------------------------------------------------------
// Attention v4: block = 256 thr = 4 waves; each wave owns 64 q (2 q-frags) of
// one q-head; block covers 256 q.  Grid 8 x 32 x 2 = 512 blocks (2/CU).
// K tile [128 k][64 d] (16 KB) and V^T tile [64 d][128 k] (16 KB) staged via
// global_load_lds with source-side XOR chunk swizzle (conflict-free b128 reads).
// S^T = K*Q^T, O^T = V^T*P^T with in-register P^T B-frags.  No online max.
// ---------------------------------------------------------------------------

__global__ __launch_bounds__(256, 2) void attn_kernel(const unsigned short* __restrict__ Qb,
                                                      const unsigned short* __restrict__ Kb,
                                                      const unsigned short* __restrict__ Vtg,
                                                      unsigned short* __restrict__ ctx) {
    __shared__ __align__(16) unsigned short smem[16384];   // 32 KB
    unsigned short* ks = smem;           // [128 k][64 d], row 128 B, chunk-swizzled
    unsigned short* vt = smem + 8192;    // [64 d][128 k], row 256 B, chunk-swizzled

    const int qt = blockIdx.x, hq = blockIdx.y, b = blockIdx.z;
    const int kvh = hq >> 2;
    const int tid = threadIdx.x;
    const int w = tid >> 6, lane = tid & 63;
    const int l31 = lane & 31, h = lane >> 5;

    // Q B-frags for two 32-q blocks (u=0,1): B[n=q=l31][k=d], k-elem = h*8+j
    const int qbase = qt * 256 + w * 64;
    uint4 qf[2][4];
#pragma unroll
    for (int u = 0; u < 2; ++u) {
        const unsigned short* qp =
            Qb + (size_t)(b * L_SEQ + qbase + u * 32 + l31) * 2048 + hq * 64;
#pragma unroll
        for (int dh = 0; dh < 4; ++dh)
            qf[u][dh] = *(const uint4*)(qp + dh * 16 + h * 8);
    }

    f32x16 o00, o01, o10, o11;   // o[u][d-half]
#pragma unroll
    for (int r = 0; r < 16; ++r) { o00[r] = 0.f; o01[r] = 0.f; o10[r] = 0.f; o11[r] = 0.f; }
    float l_acc0 = 0.f, l_acc1 = 0.f;

    const size_t kbase = (size_t)(b * L_SEQ) * KV_COLS + kvh * 64;
    const size_t vbase = (size_t)((b * 8 + kvh) * 64) * 2048;

    const int rrk = lane >> 3, cpk = lane & 7;      // K staging: 8 rows x 8 chunks
    const int drv = lane >> 4, cpv = lane & 15;     // V staging: 4 rows x 16 chunks

    for (int t = 0; t < 16; ++t) {
        const int k0 = t * 128;
        // ---- stage K [128][64]: 16 x 1KB blocks (8 rows each), swizzled ----
#pragma unroll
        for (int s = 0; s < 4; ++s) {
            const int blkk = w * 4 + s;
            gl_lds16(Kb + kbase + (size_t)(k0 + blkk * 8 + rrk) * KV_COLS + ((cpk ^ rrk) * 8),
                     ks + blkk * 512);
            const int blkv = w * 4 + s;              // V: 4 d-rows per 1KB block
            const int d = blkv * 4 + drv;
            gl_lds16(Vtg + vbase + (size_t)d * 2048 + k0 + ((cpv ^ (d & 15)) * 8),
                     vt + blkv * 512);
        }
        __syncthreads();

#pragma unroll
        for (int c = 0; c < 4; ++c) {
            // ---- K A-frags (shared across both q-blocks) ----
            uint4 kf[4];
#pragma unroll
            for (int dh = 0; dh < 4; ++dh)
                kf[dh] = *(const uint4*)&ks[(c * 32 + l31) * 64 +
                                            (((dh * 2 + h) ^ (l31 & 7)) * 8)];
            // ---- S^T and exp for u=0,1 ----
            unsigned E0[4][2], E1[4][2];
#pragma unroll
            for (int u = 0; u < 2; ++u) {
                f32x16 s;
#pragma unroll
                for (int r = 0; r < 16; ++r) s[r] = 0.f;
#pragma unroll
                for (int dh = 0; dh < 4; ++dh) s = mfma32(kf[dh], qf[u][dh], s);
                float lsum = 0.f;
#pragma unroll
                for (int g = 0; g < 4; ++g) {
                    float e0 = EXP2F(s[4 * g + 0]);
                    float e1 = EXP2F(s[4 * g + 1]);
                    float e2 = EXP2F(s[4 * g + 2]);
                    float e3 = EXP2F(s[4 * g + 3]);
                    lsum += (e0 + e1) + (e2 + e3);
                    if (u == 0) { E0[g][0] = pk_bf16(e0, e1); E0[g][1] = pk_bf16(e2, e3); }
                    else        { E1[g][0] = pk_bf16(e0, e1); E1[g][1] = pk_bf16(e2, e3); }
                }
                if (u == 0) l_acc0 += lsum; else l_acc1 += lsum;
            }
            // ---- PV: V frags shared across both q-blocks ----
            const int posv = (c * 4) ^ (l31 & 15);   // tau/h folded below via XOR
#pragma unroll
            for (int tau = 0; tau < 2; ++tau) {
                const int pos = ((c * 4 + tau * 2 + h) ^ (l31 & 15)) * 8;
                uint4 vf0 = *(const uint4*)&vt[(size_t)l31 * 128 + pos];
                uint4 vf1 = *(const uint4*)&vt[(size_t)(32 + l31) * 128 + pos];
                // u = 0
                {
                    unsigned pub0 = h ? E0[2 * tau][0] : E0[2 * tau + 1][0];
                    unsigned pub1 = h ? E0[2 * tau][1] : E0[2 * tau + 1][1];
                    unsigned R0 = (unsigned)__shfl_xor((int)pub0, 32, 64);
                    unsigned R1 = (unsigned)__shfl_xor((int)pub1, 32, 64);
                    uint4 pf;
                    pf.x = h ? R0 : E0[2 * tau][0];
                    pf.y = h ? R1 : E0[2 * tau][1];
                    pf.z = h ? E0[2 * tau + 1][0] : R0;
                    pf.w = h ? E0[2 * tau + 1][1] : R1;
                    o00 = mfma32(vf0, pf, o00);
                    o01 = mfma32(vf1, pf, o01);
                }
                // u = 1
                {
                    unsigned pub0 = h ? E1[2 * tau][0] : E1[2 * tau + 1][0];
                    unsigned pub1 = h ? E1[2 * tau][1] : E1[2 * tau + 1][1];
                    unsigned R0 = (unsigned)__shfl_xor((int)pub0, 32, 64);
                    unsigned R1 = (unsigned)__shfl_xor((int)pub1, 32, 64);
                    uint4 pf;
                    pf.x = h ? R0 : E1[2 * tau][0];
                    pf.y = h ? R1 : E1[2 * tau][1];
                    pf.z = h ? E1[2 * tau + 1][0] : R0;
                    pf.w = h ? E1[2 * tau + 1][1] : R1;
                    o10 = mfma32(vf0, pf, o10);
                    o11 = mfma32(vf1, pf, o11);
                }
            }
            (void)posv;
        }
        __syncthreads();
    }

    // ---- epilogue: per-u normalize + transpose via per-wave LDS + store ----
    __syncthreads();   // all waves done with ks/vt
    unsigned* ep = (unsigned*)smem + w * 1088;   // 32 rows x 34 dwords = 4352 B
#pragma unroll
    for (int u = 0; u < 2; ++u) {
        const float la = u ? l_acc1 : l_acc0;
        const float l_tot = la + __shfl_xor(la, 32, 64);
        const float rl = 1.f / l_tot;
#pragma unroll
        for (int dt = 0; dt < 2; ++dt) {
            const f32x16& o = u ? (dt ? o11 : o10) : (dt ? o01 : o00);
#pragma unroll
            for (int g = 0; g < 4; ++g)
#pragma unroll
                for (int p = 0; p < 2; ++p) {
                    const int dv = dt * 16 + 4 * g + 2 * h + p;
                    ep[l31 * 34 + dv] =
                        pk_bf16(o[4 * g + 2 * p] * rl, o[4 * g + 2 * p + 1] * rl);
                }
        }
        __builtin_amdgcn_s_waitcnt(0);   // wave-local LDS write->read ordering
#pragma unroll
        for (int p = 0; p < 4; ++p) {
            const int qr = (lane >> 3) + p * 8;
            const int cch = lane & 7;
            uint4 vv = *(const uint4*)((const unsigned short*)ep + qr * 68 + cch * 8);
            *(uint4*)(ctx + (size_t)(b * L_SEQ + qbase + u * 32 + qr) * 2048 +
                      hq * 64 + cch * 8) = vv;
        }
        __builtin_amdgcn_s_waitcnt(0);   // reads drained before next-u overwrite
    }
}

// ---------------------------------------------------------------------------

extern "C" void kernel_launch(void* const* d_in, const int* in_sizes, int n_in,
                              void* d_out, int out_size, void* d_ws, size_t ws_size,
                              hipStream_t stream) {
    const float* x  = (const float*)d_in[0];
    const float* Wq = (const float*)d_in[1];
    const float* bq = (const float*)d_in[2];
    const float* Wk = (const float*)d_in[3];
    const float* bk = (const float*)d_in[4];
    const float* Wv = (const float*)d_in[5];
    const float* bv = (const float*)d_in[6];
    const float* Wo = (const float*)d_in[7];
    const float* bo = (const float*)d_in[8];
    float* out = (float*)d_out;

    char* ws = (char*)d_ws;
    size_t off = 0;
    auto alloc = [&](size_t bytes) {
        char* p = ws + off;
        off += (bytes + 255) & ~(size_t)255;
        return p;
    };
    unsigned short* Wqkvt = (unsigned short*)alloc((size_t)3072 * 2048 * 2);
    unsigned short* Wot   = (unsigned short*)alloc((size_t)2048 * 2048 * 2);
    unsigned short* Xb    = (unsigned short*)alloc((size_t)M_ROWS * 2048 * 2);
    unsigned short* Qb    = (unsigned short*)alloc((size_t)M_ROWS * 2048 * 2);
    unsigned short* Kb    = (unsigned short*)alloc((size_t)M_ROWS * KV_COLS * 2);
    unsigned short* Vb    = (unsigned short*)alloc((size_t)M_ROWS * KV_COLS * 2);
    unsigned short* Vt    = (unsigned short*)alloc((size_t)M_ROWS * KV_COLS * 2);
    unsigned short* Cb    = Xb;   // Xb dead after GEMM1; attn writes ctx here

    cast_x_kernel<<<(M_ROWS * 2048 / 4 + 255) / 256, 256, 0, stream>>>(x, Xb,
                                                                       M_ROWS * 2048 / 4);
    transpose_cast_kernel<<<dim3(64, 64), 256, 0, stream>>>(Wq, Wqkvt, 2048, 0);
    transpose_cast_kernel<<<dim3(16, 64), 256, 0, stream>>>(Wk, Wqkvt, 512, 2048);
    transpose_cast_kernel<<<dim3(16, 64), 256, 0, stream>>>(Wv, Wqkvt, 512, 2560);
    transpose_cast_kernel<<<dim3(64, 64), 256, 0, stream>>>(Wo, Wot, 2048, 0);
    gemm_qkv_kernel<<<dim3(32, 24), 256, 0, stream>>>(Xb, Wqkvt, bq, bk, bv, Qb, Kb, Vb);
    transpose_v_kernel<<<dim3(16, 64, 2), 256, 0, stream>>>(Vb, Vt);
    attn_kernel<<<dim3(8, 32, 2), 256, 0, stream>>>(Qb, Kb, Vt, Cb);
    gemm_out_kernel<<<dim3(32, 16), 256, 0, stream>>>(Cb, Wot, bo, out);
}